// Round 1
// baseline (270.181 us; speedup 1.0000x reference)
//
#include <hip/hip_runtime.h>

#define NN 50000
#define NE 800000
#define CAP 64   // max in-degree slots; Poisson(16) tail P(>=64) ~ 1e-19

// ---------------- graph build ----------------

__global__ __launch_bounds__(256) void build_ell(const int* __restrict__ ei,
                                                 int* __restrict__ cnt,
                                                 int* __restrict__ ell) {
    int e = blockIdx.x * 256 + threadIdx.x;
    if (e >= NE) return;
    int s = ei[e];        // edge_index[0][e]
    int d = ei[NE + e];   // edge_index[1][e]
    int pos = atomicAdd(&cnt[d], 1);
    if (pos < CAP) ell[d * CAP + pos] = s;
}

__global__ __launch_bounds__(256) void calc_dis(const int* __restrict__ cnt,
                                                float* __restrict__ dis) {
    int i = blockIdx.x * 256 + threadIdx.x;
    if (i >= NN) return;
    // deg includes self-loop => cnt+1 >= 1 always
    dis[i] = rsqrtf((float)(cnt[i] + 1));
}

// ---------------- fp32 GEMM, K=128 fixed ----------------
// Block: 256 threads, tile 128 rows x NOUT cols, per-thread 8 x (NOUT/16).
// A staged transposed in LDS so compute reads are float4 broadcasts.

template <int NOUT>
__global__ __launch_bounds__(256) void gemm_k128(const float* __restrict__ A,
                                                 const float* __restrict__ W,
                                                 float* __restrict__ C, int M) {
    constexpr int CT = NOUT / 16;           // cols per thread: 8 or 4
    __shared__ float Al[8][132];            // Al[k][row], padded stride
    __shared__ float Wl[8][NOUT + 4];

    const int tid  = threadIdx.x;
    const int tcol = tid & 15;              // 0..15
    const int trow = tid >> 4;              // 0..15
    const int row0 = blockIdx.x * 128;

    float acc[8][CT];
#pragma unroll
    for (int i = 0; i < 8; ++i)
#pragma unroll
        for (int j = 0; j < CT; ++j) acc[i][j] = 0.0f;

    // A staging map: 128 rows x 8 k = 256 float4
    const int lrow = tid >> 1;              // 0..127
    const int lk4  = (tid & 1) * 4;         // 0 or 4
    const bool rv  = (row0 + lrow) < M;
    const float* arow = A + (size_t)(row0 + lrow) * 128;

    // W staging map: 8 k-rows x NOUT cols
    constexpr int W4 = 8 * NOUT / 4;        // 256 or 128 float4
    const int wkrow = tid / (NOUT / 4);
    const int wc4   = (tid % (NOUT / 4)) * 4;

    for (int kt = 0; kt < 128; kt += 8) {
        float4 av = rv ? *(const float4*)(arow + kt + lk4)
                       : make_float4(0.f, 0.f, 0.f, 0.f);
        Al[lk4 + 0][lrow] = av.x;
        Al[lk4 + 1][lrow] = av.y;
        Al[lk4 + 2][lrow] = av.z;
        Al[lk4 + 3][lrow] = av.w;
        if (tid < W4) {
            *(float4*)&Wl[wkrow][wc4] =
                *(const float4*)(W + (size_t)(kt + wkrow) * NOUT + wc4);
        }
        __syncthreads();
#pragma unroll
        for (int k = 0; k < 8; ++k) {
            float4 a0 = *(const float4*)&Al[k][trow * 4];
            float4 a1 = *(const float4*)&Al[k][trow * 4 + 64];
            float a[8] = {a0.x, a0.y, a0.z, a0.w, a1.x, a1.y, a1.z, a1.w};
            float4 b0 = *(const float4*)&Wl[k][tcol * 4];
            if constexpr (CT == 8) {
                float4 b1 = *(const float4*)&Wl[k][tcol * 4 + 64];
                float b[8] = {b0.x, b0.y, b0.z, b0.w, b1.x, b1.y, b1.z, b1.w};
#pragma unroll
                for (int i = 0; i < 8; ++i)
#pragma unroll
                    for (int j = 0; j < 8; ++j) acc[i][j] += a[i] * b[j];
            } else {
                float b[4] = {b0.x, b0.y, b0.z, b0.w};
#pragma unroll
                for (int i = 0; i < 8; ++i)
#pragma unroll
                    for (int j = 0; j < 4; ++j) acc[i][j] += a[i] * b[j];
            }
        }
        __syncthreads();
    }

#pragma unroll
    for (int i = 0; i < 8; ++i) {
        int row = row0 + trow * 4 + ((i < 4) ? i : (64 + i - 4));
        if (row < M) {
            if constexpr (CT == 8) {
                *(float4*)&C[(size_t)row * NOUT + tcol * 4] =
                    make_float4(acc[i][0], acc[i][1], acc[i][2], acc[i][3]);
                *(float4*)&C[(size_t)row * NOUT + tcol * 4 + 64] =
                    make_float4(acc[i][4], acc[i][5], acc[i][6], acc[i][7]);
            } else {
                *(float4*)&C[(size_t)row * NOUT + tcol * 4] =
                    make_float4(acc[i][0], acc[i][1], acc[i][2], acc[i][3]);
            }
        }
    }
}

// ---------------- normalized aggregation (one wave per node) ----------------

template <int F, bool RELU>
__global__ __launch_bounds__(256) void aggregate(const float* __restrict__ H,
                                                 const int* __restrict__ ell,
                                                 const int* __restrict__ cnt,
                                                 const float* __restrict__ dis,
                                                 const float* __restrict__ bias,
                                                 float* __restrict__ out) {
    int node = (int)((blockIdx.x * 256 + threadIdx.x) >> 6);
    int lane = threadIdx.x & 63;
    if (node >= NN) return;

    int ne = min(cnt[node], CAP);
    float di = dis[node];
    // preload all edge srcs + their dis into lanes, broadcast via shfl
    int   s_l  = (lane < ne) ? ell[node * CAP + lane] : 0;
    float ds_l = (lane < ne) ? dis[s_l] : 0.0f;

    if constexpr (F == 128) {
        float ax = 0.f, ay = 0.f;
        int j = 0;
        for (; j + 4 <= ne; j += 4) {
            int s0 = __shfl(s_l, j + 0), s1 = __shfl(s_l, j + 1);
            int s2 = __shfl(s_l, j + 2), s3 = __shfl(s_l, j + 3);
            float n0 = di * __shfl(ds_l, j + 0), n1 = di * __shfl(ds_l, j + 1);
            float n2 = di * __shfl(ds_l, j + 2), n3 = di * __shfl(ds_l, j + 3);
            float2 v0 = *(const float2*)(H + (size_t)s0 * 128 + lane * 2);
            float2 v1 = *(const float2*)(H + (size_t)s1 * 128 + lane * 2);
            float2 v2 = *(const float2*)(H + (size_t)s2 * 128 + lane * 2);
            float2 v3 = *(const float2*)(H + (size_t)s3 * 128 + lane * 2);
            ax += n0 * v0.x; ay += n0 * v0.y;
            ax += n1 * v1.x; ay += n1 * v1.y;
            ax += n2 * v2.x; ay += n2 * v2.y;
            ax += n3 * v3.x; ay += n3 * v3.y;
        }
        for (; j < ne; ++j) {
            int s = __shfl(s_l, j);
            float n = di * __shfl(ds_l, j);
            float2 v = *(const float2*)(H + (size_t)s * 128 + lane * 2);
            ax += n * v.x; ay += n * v.y;
        }
        // self-loop: norm = di*di
        float2 vs = *(const float2*)(H + (size_t)node * 128 + lane * 2);
        ax += di * di * vs.x; ay += di * di * vs.y;
        ax += bias[lane * 2]; ay += bias[lane * 2 + 1];
        if (RELU) { ax = fmaxf(ax, 0.f); ay = fmaxf(ay, 0.f); }
        *(float2*)(out + (size_t)node * 128 + lane * 2) = make_float2(ax, ay);
    } else {
        float a = 0.f;
        int j = 0;
        for (; j + 4 <= ne; j += 4) {
            int s0 = __shfl(s_l, j + 0), s1 = __shfl(s_l, j + 1);
            int s2 = __shfl(s_l, j + 2), s3 = __shfl(s_l, j + 3);
            float n0 = di * __shfl(ds_l, j + 0), n1 = di * __shfl(ds_l, j + 1);
            float n2 = di * __shfl(ds_l, j + 2), n3 = di * __shfl(ds_l, j + 3);
            float v0 = H[(size_t)s0 * 64 + lane];
            float v1 = H[(size_t)s1 * 64 + lane];
            float v2 = H[(size_t)s2 * 64 + lane];
            float v3 = H[(size_t)s3 * 64 + lane];
            a += n0 * v0 + n1 * v1 + n2 * v2 + n3 * v3;
        }
        for (; j < ne; ++j) {
            int s = __shfl(s_l, j);
            float n = di * __shfl(ds_l, j);
            a += n * H[(size_t)s * 64 + lane];
        }
        a += di * di * H[(size_t)node * 64 + lane];
        a += bias[lane];
        if (RELU) a = fmaxf(a, 0.f);
        out[(size_t)node * 64 + lane] = a;
    }
}

// ---------------- launch ----------------

extern "C" void kernel_launch(void* const* d_in, const int* in_sizes, int n_in,
                              void* d_out, int out_size, void* d_ws, size_t ws_size,
                              hipStream_t stream) {
    const float* x  = (const float*)d_in[0];
    const int*   ei = (const int*)d_in[1];
    const float* W1 = (const float*)d_in[2];
    const float* b1 = (const float*)d_in[3];
    const float* W2 = (const float*)d_in[4];
    const float* b2 = (const float*)d_in[5];
    float* out = (float*)d_out;

    char* ws = (char*)d_ws;
    const size_t NPAD = 50176;  // padded node count for alignment
    int*   cnt  = (int*)ws;                                   // NN ints
    float* dis  = (float*)(ws + NPAD * 4);                    // NN floats
    int*   ell  = (int*)(ws + 2 * NPAD * 4);                  // NN*CAP ints
    float* bufA = (float*)(ws + 2 * NPAD * 4 + (size_t)NN * CAP * 4); // NN*128
    float* bufB = bufA + (size_t)NN * 128;                    // NN*128

    hipMemsetAsync(cnt, 0, NN * sizeof(int), stream);
    build_ell<<<(NE + 255) / 256, 256, 0, stream>>>(ei, cnt, ell);
    calc_dis<<<(NN + 255) / 256, 256, 0, stream>>>(cnt, dis);

    // layer 1: h1 = x @ W1 ; agg+bias+relu -> bufB
    gemm_k128<128><<<(NN + 127) / 128, 256, 0, stream>>>(x, W1, bufA, NN);
    aggregate<128, true><<<(NN + 3) / 4, 256, 0, stream>>>(bufA, ell, cnt, dis, b1, bufB);

    // layer 2: h2 = bufB @ W2 ; agg+bias -> out
    gemm_k128<64><<<(NN + 127) / 128, 256, 0, stream>>>(bufB, W2, bufA, NN);
    aggregate<64, false><<<(NN + 3) / 4, 256, 0, stream>>>(bufA, ell, cnt, dis, b2, out);
}

// Round 2
// 249.764 us; speedup vs baseline: 1.0817x; 1.0817x over previous
//
#include <hip/hip_runtime.h>

#define NN 50000
#define NE 800000
#define CAP 64   // max in-degree slots; Poisson(16) tail P(>=64) ~ 1e-19

typedef unsigned int   u32;
typedef unsigned short u16;

__device__ inline u16 f2bf(float f) {
    u32 u = __float_as_uint(f);
    u32 r = (u + 0x7FFF + ((u >> 16) & 1)) >> 16;   // RNE
    return (u16)r;
}
__device__ inline float bf_lo(u32 u) { return __uint_as_float(u << 16); }
__device__ inline float bf_hi(u32 u) { return __uint_as_float(u & 0xFFFF0000u); }

// ---------------- graph build ----------------

__global__ __launch_bounds__(256) void build_ell(const int* __restrict__ ei,
                                                 int* __restrict__ cnt,
                                                 int* __restrict__ ell) {
    int e = blockIdx.x * 256 + threadIdx.x;
    if (e >= NE) return;
    int s = ei[e];        // edge_index[0][e]
    int d = ei[NE + e];   // edge_index[1][e]
    int pos = atomicAdd(&cnt[d], 1);
    if (pos < CAP) ell[d * CAP + pos] = s;
}

__global__ __launch_bounds__(256) void calc_dis(const int* __restrict__ cnt,
                                                float* __restrict__ dis) {
    int i = blockIdx.x * 256 + threadIdx.x;
    if (i >= NN) return;
    dis[i] = rsqrtf((float)(cnt[i] + 1));  // deg includes self-loop
}

// ---------------- fp32 GEMM, K=128 fixed, bf16 output ----------------

template <int NOUT>
__global__ __launch_bounds__(256) void gemm_k128(const float* __restrict__ A,
                                                 const float* __restrict__ W,
                                                 u16* __restrict__ C, int M) {
    constexpr int CT = NOUT / 16;           // cols per thread: 8 or 4
    __shared__ float Al[8][132];            // Al[k][row], padded stride
    __shared__ float Wl[8][NOUT + 4];

    const int tid  = threadIdx.x;
    const int tcol = tid & 15;              // 0..15
    const int trow = tid >> 4;              // 0..15
    const int row0 = blockIdx.x * 128;

    float acc[8][CT];
#pragma unroll
    for (int i = 0; i < 8; ++i)
#pragma unroll
        for (int j = 0; j < CT; ++j) acc[i][j] = 0.0f;

    const int lrow = tid >> 1;              // 0..127
    const int lk4  = (tid & 1) * 4;         // 0 or 4
    const bool rv  = (row0 + lrow) < M;
    const float* arow = A + (size_t)(row0 + lrow) * 128;

    constexpr int W4 = 8 * NOUT / 4;        // 256 or 128 float4
    const int wkrow = tid / (NOUT / 4);
    const int wc4   = (tid % (NOUT / 4)) * 4;

    for (int kt = 0; kt < 128; kt += 8) {
        float4 av = rv ? *(const float4*)(arow + kt + lk4)
                       : make_float4(0.f, 0.f, 0.f, 0.f);
        Al[lk4 + 0][lrow] = av.x;
        Al[lk4 + 1][lrow] = av.y;
        Al[lk4 + 2][lrow] = av.z;
        Al[lk4 + 3][lrow] = av.w;
        if (tid < W4) {
            *(float4*)&Wl[wkrow][wc4] =
                *(const float4*)(W + (size_t)(kt + wkrow) * NOUT + wc4);
        }
        __syncthreads();
#pragma unroll
        for (int k = 0; k < 8; ++k) {
            float4 a0 = *(const float4*)&Al[k][trow * 4];
            float4 a1 = *(const float4*)&Al[k][trow * 4 + 64];
            float a[8] = {a0.x, a0.y, a0.z, a0.w, a1.x, a1.y, a1.z, a1.w};
            float4 b0 = *(const float4*)&Wl[k][tcol * 4];
            if constexpr (CT == 8) {
                float4 b1 = *(const float4*)&Wl[k][tcol * 4 + 64];
                float b[8] = {b0.x, b0.y, b0.z, b0.w, b1.x, b1.y, b1.z, b1.w};
#pragma unroll
                for (int i = 0; i < 8; ++i)
#pragma unroll
                    for (int j = 0; j < 8; ++j) acc[i][j] += a[i] * b[j];
            } else {
                float b[4] = {b0.x, b0.y, b0.z, b0.w};
#pragma unroll
                for (int i = 0; i < 8; ++i)
#pragma unroll
                    for (int j = 0; j < 4; ++j) acc[i][j] += a[i] * b[j];
            }
        }
        __syncthreads();
    }

#pragma unroll
    for (int i = 0; i < 8; ++i) {
        int row = row0 + trow * 4 + ((i < 4) ? i : (64 + i - 4));
        if (row < M) {
            *(ushort4*)&C[(size_t)row * NOUT + tcol * 4] =
                make_ushort4(f2bf(acc[i][0]), f2bf(acc[i][1]),
                             f2bf(acc[i][2]), f2bf(acc[i][3]));
            if constexpr (CT == 8) {
                *(ushort4*)&C[(size_t)row * NOUT + tcol * 4 + 64] =
                    make_ushort4(f2bf(acc[i][4]), f2bf(acc[i][5]),
                                 f2bf(acc[i][6]), f2bf(acc[i][7]));
            }
        }
    }
}

// ---------------- normalized aggregation (one wave per node, bf16 H) --------

template <int F, bool RELU>
__global__ __launch_bounds__(256) void aggregate(const u16* __restrict__ H,
                                                 const int* __restrict__ ell,
                                                 const int* __restrict__ cnt,
                                                 const float* __restrict__ dis,
                                                 const float* __restrict__ bias,
                                                 float* __restrict__ out) {
    int node = (int)((blockIdx.x * 256 + threadIdx.x) >> 6);
    int lane = threadIdx.x & 63;
    if (node >= NN) return;

    int ne = min(cnt[node], CAP);
    float di = dis[node];
    // preload all edge srcs + pre-scaled norms into lanes, broadcast via shfl
    int   s_l  = (lane < ne) ? ell[node * CAP + lane] : 0;
    float ds_l = (lane < ne) ? dis[s_l] * di : 0.0f;

    if constexpr (F == 128) {
        float ax = 0.f, ay = 0.f;
        int j = 0;
        for (; j + 8 <= ne; j += 8) {
            u32 v[8]; float n[8];
#pragma unroll
            for (int t = 0; t < 8; ++t) {
                int s = __shfl(s_l, j + t);
                n[t] = __shfl(ds_l, j + t);
                v[t] = ((const u32*)(H + (size_t)s * 128))[lane];
            }
#pragma unroll
            for (int t = 0; t < 8; ++t) {
                ax += n[t] * bf_lo(v[t]);
                ay += n[t] * bf_hi(v[t]);
            }
        }
        for (; j < ne; ++j) {
            int s = __shfl(s_l, j);
            float n = __shfl(ds_l, j);
            u32 v = ((const u32*)(H + (size_t)s * 128))[lane];
            ax += n * bf_lo(v);
            ay += n * bf_hi(v);
        }
        // self-loop: norm = di*di
        u32 vs = ((const u32*)(H + (size_t)node * 128))[lane];
        ax += di * di * bf_lo(vs);
        ay += di * di * bf_hi(vs);
        ax += bias[lane * 2]; ay += bias[lane * 2 + 1];
        if (RELU) { ax = fmaxf(ax, 0.f); ay = fmaxf(ay, 0.f); }
        *(float2*)(out + (size_t)node * 128 + lane * 2) = make_float2(ax, ay);
    } else {
        float a = 0.f;
        int j = 0;
        for (; j + 8 <= ne; j += 8) {
            u16 v[8]; float n[8];
#pragma unroll
            for (int t = 0; t < 8; ++t) {
                int s = __shfl(s_l, j + t);
                n[t] = __shfl(ds_l, j + t);
                v[t] = H[(size_t)s * 64 + lane];
            }
#pragma unroll
            for (int t = 0; t < 8; ++t)
                a += n[t] * __uint_as_float((u32)v[t] << 16);
        }
        for (; j < ne; ++j) {
            int s = __shfl(s_l, j);
            float n = __shfl(ds_l, j);
            a += n * __uint_as_float((u32)H[(size_t)s * 64 + lane] << 16);
        }
        a += di * di * __uint_as_float((u32)H[(size_t)node * 64 + lane] << 16);
        a += bias[lane];
        if (RELU) a = fmaxf(a, 0.f);
        out[(size_t)node * 64 + lane] = a;
    }
}

// ---------------- launch ----------------

extern "C" void kernel_launch(void* const* d_in, const int* in_sizes, int n_in,
                              void* d_out, int out_size, void* d_ws, size_t ws_size,
                              hipStream_t stream) {
    const float* x  = (const float*)d_in[0];
    const int*   ei = (const int*)d_in[1];
    const float* W1 = (const float*)d_in[2];
    const float* b1 = (const float*)d_in[3];
    const float* W2 = (const float*)d_in[4];
    const float* b2 = (const float*)d_in[5];
    float* out = (float*)d_out;

    char* ws = (char*)d_ws;
    const size_t NPAD = 50176;  // padded node count for alignment
    int*   cnt  = (int*)ws;                                       // NN ints
    float* dis  = (float*)(ws + NPAD * 4);                        // NN floats
    int*   ell  = (int*)(ws + 2 * NPAD * 4);                      // NN*CAP ints
    u16*   Hbf  = (u16*)(ws + 2 * NPAD * 4 + (size_t)NN * CAP * 4);   // NN*128 bf16
    float* bufB = (float*)(ws + 2 * NPAD * 4 + (size_t)NN * CAP * 4
                              + (size_t)NN * 128 * 2);            // NN*128 fp32

    hipMemsetAsync(cnt, 0, NN * sizeof(int), stream);
    build_ell<<<(NE + 255) / 256, 256, 0, stream>>>(ei, cnt, ell);
    calc_dis<<<(NN + 255) / 256, 256, 0, stream>>>(cnt, dis);

    // layer 1: h1 = x @ W1 (bf16) ; agg+bias+relu -> bufB (fp32)
    gemm_k128<128><<<(NN + 127) / 128, 256, 0, stream>>>(x, W1, Hbf, NN);
    aggregate<128, true><<<(NN + 3) / 4, 256, 0, stream>>>(Hbf, ell, cnt, dis, b1, bufB);

    // layer 2: h2 = bufB @ W2 (bf16) ; agg+bias -> out (fp32)
    gemm_k128<64><<<(NN + 127) / 128, 256, 0, stream>>>(bufB, W2, Hbf, NN);
    aggregate<64, false><<<(NN + 3) / 4, 256, 0, stream>>>(Hbf, ell, cnt, dis, b2, out);
}

// Round 3
// 239.589 us; speedup vs baseline: 1.1277x; 1.0425x over previous
//
#include <hip/hip_runtime.h>

#define NN 50000
#define NE 800000
#define CAP 64      // max in-degree slots; Poisson(16) tail P(>=64) ~ 1e-19
#define SLICE 6250  // NN / 8 nodes per XCD slice

typedef unsigned int   u32;
typedef unsigned short u16;

__device__ inline u16 f2bf(float f) {
    u32 u = __float_as_uint(f);
    u32 r = (u + 0x7FFF + ((u >> 16) & 1)) >> 16;   // RNE
    return (u16)r;
}
__device__ inline float bf_lo(u32 u) { return __uint_as_float(u << 16); }
__device__ inline float bf_hi(u32 u) { return __uint_as_float(u & 0xFFFF0000u); }

// ---------------- graph build (XCD-sliced, u16 ELL) ----------------
// Blocks with blockIdx&7 == s handle only dst nodes in [s*SLICE,(s+1)*SLICE).
// Those blocks collectively stride over ALL edges (correct regardless of the
// actual blockIdx->XCD mapping; %8 round-robin is a locality heuristic that
// keeps each slice's 0.8 MB ELL region + 25 KB counters resident in one L2).

__global__ __launch_bounds__(256) void build_ell(const int* __restrict__ ei,
                                                 int* __restrict__ cnt,
                                                 u16* __restrict__ ell) {
    const int s  = blockIdx.x & 7;
    const int g  = blockIdx.x >> 3;
    const int ng = gridDim.x >> 3;
    const int lo = s * SLICE, hi = lo + SLICE;
    for (int e0 = (g * 256 + (int)threadIdx.x) * 4; e0 < NE; e0 += ng * 1024) {
        int4 d4 = *(const int4*)(ei + NE + e0);
        int dv[4] = {d4.x, d4.y, d4.z, d4.w};
#pragma unroll
        for (int k = 0; k < 4; ++k) {
            int d = dv[k];
            if (d >= lo && d < hi) {
                int src = ei[e0 + k];
                int pos = atomicAdd(&cnt[d], 1);
                if (pos < CAP) ell[d * CAP + pos] = (u16)src;
            }
        }
    }
}

__global__ __launch_bounds__(256) void calc_dis(const int* __restrict__ cnt,
                                                float* __restrict__ dis) {
    int i = blockIdx.x * 256 + threadIdx.x;
    if (i >= NN) return;
    dis[i] = rsqrtf((float)(cnt[i] + 1));  // deg includes self-loop
}

// ---------------- fp32 GEMM, K=128 fixed, bf16 output ----------------

template <int NOUT>
__global__ __launch_bounds__(256) void gemm_k128(const float* __restrict__ A,
                                                 const float* __restrict__ W,
                                                 u16* __restrict__ C, int M) {
    constexpr int CT = NOUT / 16;           // cols per thread: 8 or 4
    __shared__ float Al[8][132];            // Al[k][row], padded stride
    __shared__ float Wl[8][NOUT + 4];

    const int tid  = threadIdx.x;
    const int tcol = tid & 15;              // 0..15
    const int trow = tid >> 4;              // 0..15
    const int row0 = blockIdx.x * 128;

    float acc[8][CT];
#pragma unroll
    for (int i = 0; i < 8; ++i)
#pragma unroll
        for (int j = 0; j < CT; ++j) acc[i][j] = 0.0f;

    const int lrow = tid >> 1;              // 0..127
    const int lk4  = (tid & 1) * 4;         // 0 or 4
    const bool rv  = (row0 + lrow) < M;
    const float* arow = A + (size_t)(row0 + lrow) * 128;

    constexpr int W4 = 8 * NOUT / 4;        // 256 or 128 float4
    const int wkrow = tid / (NOUT / 4);
    const int wc4   = (tid % (NOUT / 4)) * 4;

    for (int kt = 0; kt < 128; kt += 8) {
        float4 av = rv ? *(const float4*)(arow + kt + lk4)
                       : make_float4(0.f, 0.f, 0.f, 0.f);
        Al[lk4 + 0][lrow] = av.x;
        Al[lk4 + 1][lrow] = av.y;
        Al[lk4 + 2][lrow] = av.z;
        Al[lk4 + 3][lrow] = av.w;
        if (tid < W4) {
            *(float4*)&Wl[wkrow][wc4] =
                *(const float4*)(W + (size_t)(kt + wkrow) * NOUT + wc4);
        }
        __syncthreads();
#pragma unroll
        for (int k = 0; k < 8; ++k) {
            float4 a0 = *(const float4*)&Al[k][trow * 4];
            float4 a1 = *(const float4*)&Al[k][trow * 4 + 64];
            float a[8] = {a0.x, a0.y, a0.z, a0.w, a1.x, a1.y, a1.z, a1.w};
            float4 b0 = *(const float4*)&Wl[k][tcol * 4];
            if constexpr (CT == 8) {
                float4 b1 = *(const float4*)&Wl[k][tcol * 4 + 64];
                float b[8] = {b0.x, b0.y, b0.z, b0.w, b1.x, b1.y, b1.z, b1.w};
#pragma unroll
                for (int i = 0; i < 8; ++i)
#pragma unroll
                    for (int j = 0; j < 8; ++j) acc[i][j] += a[i] * b[j];
            } else {
                float b[4] = {b0.x, b0.y, b0.z, b0.w};
#pragma unroll
                for (int i = 0; i < 8; ++i)
#pragma unroll
                    for (int j = 0; j < 4; ++j) acc[i][j] += a[i] * b[j];
            }
        }
        __syncthreads();
    }

#pragma unroll
    for (int i = 0; i < 8; ++i) {
        int row = row0 + trow * 4 + ((i < 4) ? i : (64 + i - 4));
        if (row < M) {
            *(ushort4*)&C[(size_t)row * NOUT + tcol * 4] =
                make_ushort4(f2bf(acc[i][0]), f2bf(acc[i][1]),
                             f2bf(acc[i][2]), f2bf(acc[i][3]));
            if constexpr (CT == 8) {
                *(ushort4*)&C[(size_t)row * NOUT + tcol * 4 + 64] =
                    make_ushort4(f2bf(acc[i][4]), f2bf(acc[i][5]),
                                 f2bf(acc[i][6]), f2bf(acc[i][7]));
            }
        }
    }
}

// ---------------- normalized aggregation (one wave per node, bf16 H) --------

template <int F, bool RELU>
__global__ __launch_bounds__(256) void aggregate(const u16* __restrict__ H,
                                                 const u16* __restrict__ ell,
                                                 const int* __restrict__ cnt,
                                                 const float* __restrict__ dis,
                                                 const float* __restrict__ bias,
                                                 float* __restrict__ out) {
    int node = (int)((blockIdx.x * 256 + threadIdx.x) >> 6);
    int lane = threadIdx.x & 63;
    if (node >= NN) return;

    int ne = min(cnt[node], CAP);
    float di = dis[node];
    // preload all edge srcs + pre-scaled norms into lanes, broadcast via shfl
    int   s_l  = (lane < ne) ? (int)ell[node * CAP + lane] : 0;
    float ds_l = (lane < ne) ? dis[s_l] * di : 0.0f;

    if constexpr (F == 128) {
        float ax = 0.f, ay = 0.f;
        int j = 0;
        for (; j + 8 <= ne; j += 8) {
            u32 v[8]; float n[8];
#pragma unroll
            for (int t = 0; t < 8; ++t) {
                int s = __shfl(s_l, j + t);
                n[t] = __shfl(ds_l, j + t);
                v[t] = ((const u32*)(H + (size_t)s * 128))[lane];
            }
#pragma unroll
            for (int t = 0; t < 8; ++t) {
                ax += n[t] * bf_lo(v[t]);
                ay += n[t] * bf_hi(v[t]);
            }
        }
        for (; j < ne; ++j) {
            int s = __shfl(s_l, j);
            float n = __shfl(ds_l, j);
            u32 v = ((const u32*)(H + (size_t)s * 128))[lane];
            ax += n * bf_lo(v);
            ay += n * bf_hi(v);
        }
        // self-loop: norm = di*di
        u32 vs = ((const u32*)(H + (size_t)node * 128))[lane];
        ax += di * di * bf_lo(vs);
        ay += di * di * bf_hi(vs);
        ax += bias[lane * 2]; ay += bias[lane * 2 + 1];
        if (RELU) { ax = fmaxf(ax, 0.f); ay = fmaxf(ay, 0.f); }
        *(float2*)(out + (size_t)node * 128 + lane * 2) = make_float2(ax, ay);
    } else {
        float a = 0.f;
        int j = 0;
        for (; j + 8 <= ne; j += 8) {
            u16 v[8]; float n[8];
#pragma unroll
            for (int t = 0; t < 8; ++t) {
                int s = __shfl(s_l, j + t);
                n[t] = __shfl(ds_l, j + t);
                v[t] = H[(size_t)s * 64 + lane];
            }
#pragma unroll
            for (int t = 0; t < 8; ++t)
                a += n[t] * __uint_as_float((u32)v[t] << 16);
        }
        for (; j < ne; ++j) {
            int s = __shfl(s_l, j);
            float n = __shfl(ds_l, j);
            a += n * __uint_as_float((u32)H[(size_t)s * 64 + lane] << 16);
        }
        a += di * di * __uint_as_float((u32)H[(size_t)node * 64 + lane] << 16);
        a += bias[lane];
        if (RELU) a = fmaxf(a, 0.f);
        out[(size_t)node * 64 + lane] = a;
    }
}

// ---------------- launch ----------------

extern "C" void kernel_launch(void* const* d_in, const int* in_sizes, int n_in,
                              void* d_out, int out_size, void* d_ws, size_t ws_size,
                              hipStream_t stream) {
    const float* x  = (const float*)d_in[0];
    const int*   ei = (const int*)d_in[1];
    const float* W1 = (const float*)d_in[2];
    const float* b1 = (const float*)d_in[3];
    const float* W2 = (const float*)d_in[4];
    const float* b2 = (const float*)d_in[5];
    float* out = (float*)d_out;

    char* ws = (char*)d_ws;
    const size_t NPAD = 50176;  // padded node count for alignment
    int*   cnt  = (int*)ws;                                       // NN ints
    float* dis  = (float*)(ws + NPAD * 4);                        // NN floats
    u16*   ell  = (u16*)(ws + 2 * NPAD * 4);                      // NN*CAP u16
    u16*   Hbf  = (u16*)(ws + 2 * NPAD * 4 + (size_t)NN * CAP * 2);   // NN*128 bf16
    float* bufB = (float*)(ws + 2 * NPAD * 4 + (size_t)NN * CAP * 2
                              + (size_t)NN * 128 * 2);            // NN*128 fp32

    hipMemsetAsync(cnt, 0, NN * sizeof(int), stream);
    build_ell<<<1600, 256, 0, stream>>>(ei, cnt, ell);
    calc_dis<<<(NN + 255) / 256, 256, 0, stream>>>(cnt, dis);

    // layer 1: h1 = x @ W1 (bf16) ; agg+bias+relu -> bufB (fp32)
    gemm_k128<128><<<(NN + 127) / 128, 256, 0, stream>>>(x, W1, Hbf, NN);
    aggregate<128, true><<<(NN + 3) / 4, 256, 0, stream>>>(Hbf, ell, cnt, dis, b1, bufB);

    // layer 2: h2 = bufB @ W2 (bf16) ; agg+bias -> out (fp32)
    gemm_k128<64><<<(NN + 127) / 128, 256, 0, stream>>>(bufB, W2, Hbf, NN);
    aggregate<64, false><<<(NN + 3) / 4, 256, 0, stream>>>(Hbf, ell, cnt, dis, b2, out);
}

// Round 4
// 202.664 us; speedup vs baseline: 1.3331x; 1.1822x over previous
//
#include <hip/hip_runtime.h>

#define NN 50000
#define NE 800000
#define CAP 64      // max in-degree slots; Poisson(16) tail P(>=64) ~ 1e-19
#define SLICE 6250  // NN / 8 nodes per XCD slice

typedef unsigned int   u32;
typedef unsigned short u16;
typedef __attribute__((ext_vector_type(8))) short short8;  // 8 bf16 in 4 VGPRs
typedef __attribute__((ext_vector_type(4))) float f32x4;

__device__ inline u16 f2bf(float f) {
    u32 u = __float_as_uint(f);
    return (u16)((u + 0x7FFF + ((u >> 16) & 1)) >> 16);   // RNE
}
__device__ inline float bfval(u16 h) { return __uint_as_float(((u32)h) << 16); }
__device__ inline float bf_lo(u32 u) { return __uint_as_float(u << 16); }
__device__ inline float bf_hi(u32 u) { return __uint_as_float(u & 0xFFFF0000u); }

// ---------------- graph build (XCD-sliced, u16 ELL) ----------------

__global__ __launch_bounds__(256) void build_ell(const int* __restrict__ ei,
                                                 int* __restrict__ cnt,
                                                 u16* __restrict__ ell) {
    const int s  = blockIdx.x & 7;
    const int g  = blockIdx.x >> 3;
    const int ng = gridDim.x >> 3;
    const int lo = s * SLICE, hi = lo + SLICE;
    for (int e0 = (g * 256 + (int)threadIdx.x) * 4; e0 < NE; e0 += ng * 1024) {
        int4 d4 = *(const int4*)(ei + NE + e0);
        int dv[4] = {d4.x, d4.y, d4.z, d4.w};
#pragma unroll
        for (int k = 0; k < 4; ++k) {
            int d = dv[k];
            if (d >= lo && d < hi) {
                int src = ei[e0 + k];
                int pos = atomicAdd(&cnt[d], 1);
                if (pos < CAP) ell[d * CAP + pos] = (u16)src;
            }
        }
    }
}

// ---------------- W pre-swizzle into MFMA B-fragment order, bf16 hi/lo ------
// Flat layout: Wf[((t*4 + kc)*64 + lane)*8 + j] = W[kc*32 + (lane>>4)*8 + j][t*16 + (lane&15)]
// so a lane's B-frag for (col-tile t, K-chunk kc) is one 16B load.

__global__ __launch_bounds__(256) void prep_w(const float* __restrict__ W1,
                                              const float* __restrict__ W2,
                                              u16* __restrict__ W1h, u16* __restrict__ W1l,
                                              u16* __restrict__ W2h, u16* __restrict__ W2l) {
    int i = blockIdx.x * 256 + threadIdx.x;
    const float* W; u16 *Dh, *Dl; int NOUT, idx;
    if (i < 16384) { W = W1; Dh = W1h; Dl = W1l; NOUT = 128; idx = i; }
    else           { idx = i - 16384; if (idx >= 8192) return;
                     W = W2; Dh = W2h; Dl = W2l; NOUT = 64; }
    int j = idx & 7, l = (idx >> 3) & 63, kc = (idx >> 9) & 3, t = idx >> 11;
    int k = kc * 32 + (l >> 4) * 8 + j;
    int n = t * 16 + (l & 15);
    float w = W[k * NOUT + n];
    u16 h = f2bf(w);
    Dh[idx] = h;
    Dl[idx] = f2bf(w - bfval(h));
}

// ---------------- MFMA GEMM, K=128, fp32 A via 3-term bf16 split ------------
// D = A*W: A_hi*W_hi + A_lo*W_hi + A_hi*W_lo  (residual ~2^-18, fp32-grade).
// Block = 4 waves x 16 rows; no LDS: A-frags built in registers, B-frags are
// 16B global loads from the pre-swizzled W (96KB total, L1/L2-resident).

template <int NOUT>
__global__ __launch_bounds__(256) void gemm_mfma(const float* __restrict__ A,
                                                 const u16* __restrict__ Wh,
                                                 const u16* __restrict__ Wl,
                                                 u16* __restrict__ C, int M) {
    constexpr int NT = NOUT / 16;
    const int tid = threadIdx.x;
    const int w = tid >> 6, l = tid & 63;
    const int m = l & 15, q = l >> 4;

    int arow = blockIdx.x * 64 + w * 16 + m;
    const float* Ar = A + (size_t)min(arow, M - 1) * 128;

    f32x4 acc[NT] = {};

#pragma unroll
    for (int kc = 0; kc < 4; ++kc) {
        float p[8];
        *(float4*)&p[0] = *(const float4*)(Ar + kc * 32 + q * 8);
        *(float4*)&p[4] = *(const float4*)(Ar + kc * 32 + q * 8 + 4);
        short8 ah, al;
#pragma unroll
        for (int j = 0; j < 8; ++j) {
            u16 h = f2bf(p[j]);
            ah[j] = (short)h;
            al[j] = (short)f2bf(p[j] - bfval(h));
        }
#pragma unroll
        for (int t = 0; t < NT; ++t) {
            size_t bo = ((size_t)(t * 4 + kc) * 64 + l) * 8;
            short8 bh = *(const short8*)(Wh + bo);
            short8 bl = *(const short8*)(Wl + bo);
            acc[t] = __builtin_amdgcn_mfma_f32_16x16x32_bf16(ah, bh, acc[t], 0, 0, 0);
            acc[t] = __builtin_amdgcn_mfma_f32_16x16x32_bf16(al, bh, acc[t], 0, 0, 0);
            acc[t] = __builtin_amdgcn_mfma_f32_16x16x32_bf16(ah, bl, acc[t], 0, 0, 0);
        }
    }

    // D layout: col = lane&15, row = (lane>>4)*4 + reg  [m89/m91 verified]
    int growbase = blockIdx.x * 64 + w * 16 + q * 4;
#pragma unroll
    for (int t = 0; t < NT; ++t)
#pragma unroll
        for (int r = 0; r < 4; ++r) {
            int grow = growbase + r;
            if (grow < M) C[(size_t)grow * NOUT + t * 16 + m] = f2bf(acc[t][r]);
        }
}

// ---------------- normalized aggregation (one wave per node, bf16 H) --------
// 64 lanes partitioned into G groups; each group gathers one edge-row slice of
// 16B per step (dwordx4). Per-group partials merged by butterfly at the end.
// Self-loop folded in as edge #ne (dis[node]*dis[node]); rsqrt fused (no dis[]).

template <int F, bool RELU>
__global__ __launch_bounds__(256) void aggregate(const u16* __restrict__ H,
                                                 const u16* __restrict__ ell,
                                                 const int* __restrict__ cnt,
                                                 const float* __restrict__ bias,
                                                 float* __restrict__ out) {
    const int tid = threadIdx.x;
    const int node = (int)((blockIdx.x * 256 + tid) >> 6);
    if (node >= NN) return;
    const int lane = tid & 63;

    const int cn = cnt[node];
    const int ne = min(cn, 63);            // keep lane for self-loop
    const float di = rsqrtf((float)(cn + 1));
    int   s_l = (lane < ne) ? (int)ell[(size_t)node * CAP + lane] : node;
    float n_l = (lane <= ne) ? rsqrtf((float)(cnt[s_l] + 1)) * di : 0.0f;

    constexpr int G = (F == 128) ? 4 : 8;  // edges gathered per step
    constexpr int L = 64 / G;              // lanes per edge (16B each)
    const int g = lane / L;
    const int ci = lane & (L - 1);

    const int m = ne + 1;
    const int mPad = (m + 2 * G - 1) & ~(2 * G - 1);   // <= 64 since m <= 64

    float acc[8] = {0, 0, 0, 0, 0, 0, 0, 0};
    for (int j = 0; j < mPad; j += 2 * G) {
        int   sA = __shfl(s_l, j + g);
        float nA = __shfl(n_l, j + g);
        int   sB = __shfl(s_l, j + G + g);
        float nB = __shfl(n_l, j + G + g);
        uint4 vA = *(const uint4*)(H + (size_t)sA * F + ci * 8);
        uint4 vB = *(const uint4*)(H + (size_t)sB * F + ci * 8);
        acc[0] += nA * bf_lo(vA.x); acc[1] += nA * bf_hi(vA.x);
        acc[2] += nA * bf_lo(vA.y); acc[3] += nA * bf_hi(vA.y);
        acc[4] += nA * bf_lo(vA.z); acc[5] += nA * bf_hi(vA.z);
        acc[6] += nA * bf_lo(vA.w); acc[7] += nA * bf_hi(vA.w);
        acc[0] += nB * bf_lo(vB.x); acc[1] += nB * bf_hi(vB.x);
        acc[2] += nB * bf_lo(vB.y); acc[3] += nB * bf_hi(vB.y);
        acc[4] += nB * bf_lo(vB.z); acc[5] += nB * bf_hi(vB.z);
        acc[6] += nB * bf_lo(vB.w); acc[7] += nB * bf_hi(vB.w);
    }

#pragma unroll
    for (int i = 0; i < 8; ++i) {
        if (F == 64) acc[i] += __shfl_xor(acc[i], 8);
        acc[i] += __shfl_xor(acc[i], 16);
        acc[i] += __shfl_xor(acc[i], 32);
    }

    if (F == 128) {
        if (lane < 32) {
            int part = lane >> 4;
            int c0 = (lane & 15) * 8 + part * 4;
            float4 b4 = *(const float4*)(bias + c0);
            float4 o = make_float4(acc[part * 4 + 0] + b4.x, acc[part * 4 + 1] + b4.y,
                                   acc[part * 4 + 2] + b4.z, acc[part * 4 + 3] + b4.w);
            if (RELU) { o.x = fmaxf(o.x, 0.f); o.y = fmaxf(o.y, 0.f);
                        o.z = fmaxf(o.z, 0.f); o.w = fmaxf(o.w, 0.f); }
            *(float4*)(out + (size_t)node * 128 + c0) = o;
        }
    } else {
        if (lane < 16) {
            int part = (lane >> 3) & 1;
            int c0 = (lane & 7) * 8 + part * 4;
            float4 b4 = *(const float4*)(bias + c0);
            float4 o = make_float4(acc[part * 4 + 0] + b4.x, acc[part * 4 + 1] + b4.y,
                                   acc[part * 4 + 2] + b4.z, acc[part * 4 + 3] + b4.w);
            if (RELU) { o.x = fmaxf(o.x, 0.f); o.y = fmaxf(o.y, 0.f);
                        o.z = fmaxf(o.z, 0.f); o.w = fmaxf(o.w, 0.f); }
            *(float4*)(out + (size_t)node * 64 + c0) = o;
        }
    }
}

// ---------------- launch ----------------

extern "C" void kernel_launch(void* const* d_in, const int* in_sizes, int n_in,
                              void* d_out, int out_size, void* d_ws, size_t ws_size,
                              hipStream_t stream) {
    const float* x  = (const float*)d_in[0];
    const int*   ei = (const int*)d_in[1];
    const float* W1 = (const float*)d_in[2];
    const float* b1 = (const float*)d_in[3];
    const float* W2 = (const float*)d_in[4];
    const float* b2 = (const float*)d_in[5];
    float* out = (float*)d_out;

    char* ws = (char*)d_ws;
    size_t off = 0;
    int* cnt = (int*)ws;                     off += (size_t)51200 * 4;
    u16* ell = (u16*)(ws + off);             off += (size_t)NN * CAP * 2;
    off = (off + 255) & ~(size_t)255;
    u16* W1h = (u16*)(ws + off);             off += 16384 * 2;
    u16* W1l = (u16*)(ws + off);             off += 16384 * 2;
    u16* W2h = (u16*)(ws + off);             off += 8192 * 2;
    u16* W2l = (u16*)(ws + off);             off += 8192 * 2;
    off = (off + 255) & ~(size_t)255;
    u16* Hbf = (u16*)(ws + off);             off += (size_t)NN * 128 * 2;
    float* bufB = (float*)(ws + off);        off += (size_t)NN * 128 * 4;

    hipMemsetAsync(cnt, 0, NN * sizeof(int), stream);
    prep_w<<<96, 256, 0, stream>>>(W1, W2, W1h, W1l, W2h, W2l);
    build_ell<<<1600, 256, 0, stream>>>(ei, cnt, ell);

    // layer 1: H1 = x@W1 (bf16 out) ; agg+bias+relu -> bufB (fp32)
    gemm_mfma<128><<<(NN + 63) / 64, 256, 0, stream>>>(x, W1h, W1l, Hbf, NN);
    aggregate<128, true><<<(NN + 3) / 4, 256, 0, stream>>>(Hbf, ell, cnt, b1, bufB);

    // layer 2: H2 = bufB@W2 (bf16 out) ; agg+bias -> out (fp32)
    gemm_mfma<64><<<(NN + 63) / 64, 256, 0, stream>>>(bufB, W2h, W2l, Hbf, NN);
    aggregate<64, false><<<(NN + 3) / 4, 256, 0, stream>>>(Hbf, ell, cnt, b2, out);
}

// Round 5
// 196.927 us; speedup vs baseline: 1.3720x; 1.0291x over previous
//
#include <hip/hip_runtime.h>

#define NN 50000
#define NE 800000
#define CAP 64        // 2 shards x 32 slots
#define NPAD 50176    // counter array stride (line-separated shards)
#define SLICE 6250    // NN / 8 nodes per XCD slice

typedef unsigned int   u32;
typedef unsigned short u16;
typedef __attribute__((ext_vector_type(8))) short short8;  // 8 bf16 in 4 VGPRs
typedef __attribute__((ext_vector_type(4))) float f32x4;

__device__ inline u16 f2bf(float f) {
    u32 u = __float_as_uint(f);
    return (u16)((u + 0x7FFF + ((u >> 16) & 1)) >> 16);   // RNE
}
__device__ inline float bfval(u16 h) { return __uint_as_float(((u32)h) << 16); }
__device__ inline float bf_lo(u32 u) { return __uint_as_float(u << 16); }
__device__ inline float bf_hi(u32 u) { return __uint_as_float(u & 0xFFFF0000u); }

// ---------------- graph build (XCD-sliced, 2-way sharded counters) ----------
// Shard 0 counters at cnt[d], shard 1 at cnt[NPAD+d] (different cache lines).
// Shard s owns ELL slots [s*32, s*32+32). Halves same-line atomic serialization.

__global__ __launch_bounds__(256) void build_ell(const int* __restrict__ ei,
                                                 int* __restrict__ cnt,
                                                 u16* __restrict__ ell) {
    const int s  = blockIdx.x & 7;
    const int g  = blockIdx.x >> 3;
    const int ng = gridDim.x >> 3;
    const int lo = s * SLICE, hi = lo + SLICE;
    for (int e0 = (g * 256 + (int)threadIdx.x) * 4; e0 < NE; e0 += ng * 1024) {
        int4 d4 = *(const int4*)(ei + NE + e0);
        int dv[4] = {d4.x, d4.y, d4.z, d4.w};
#pragma unroll
        for (int k = 0; k < 4; ++k) {
            int d = dv[k];
            if (d >= lo && d < hi) {
                int src = ei[e0 + k];
                int sh = k & 1;
                int pos = atomicAdd(&cnt[sh * NPAD + d], 1);
                if (pos < 32) ell[d * CAP + sh * 32 + pos] = (u16)src;
            }
        }
    }
}

// ---------------- W pre-swizzle + counter zeroing ----------------
// Wf[((t*4 + kc)*64 + lane)*8 + j] = W[kc*32 + (lane>>4)*8 + j][t*16 + (lane&15)]

__global__ __launch_bounds__(256) void prep_w(const float* __restrict__ W1,
                                              const float* __restrict__ W2,
                                              u16* __restrict__ W1h, u16* __restrict__ W1l,
                                              u16* __restrict__ W2h, u16* __restrict__ W2l,
                                              int* __restrict__ cnt) {
    int i = blockIdx.x * 256 + threadIdx.x;           // grid 128 -> 32768 threads
    for (int z = i; z < 2 * NPAD; z += 32768) cnt[z] = 0;
    const float* W; u16 *Dh, *Dl; int NOUT, idx;
    if (i < 16384) { W = W1; Dh = W1h; Dl = W1l; NOUT = 128; idx = i; }
    else           { idx = i - 16384; if (idx >= 8192) return;
                     W = W2; Dh = W2h; Dl = W2l; NOUT = 64; }
    int j = idx & 7, l = (idx >> 3) & 63, kc = (idx >> 9) & 3, t = idx >> 11;
    int k = kc * 32 + (l >> 4) * 8 + j;
    int n = t * 16 + (l & 15);
    float w = W[k * NOUT + n];
    u16 h = f2bf(w);
    Dh[idx] = h;
    Dl[idx] = f2bf(w - bfval(h));
}

// ---------------- MFMA GEMM, K=128, fp32 A via 3-term bf16 split ------------

template <int NOUT>
__global__ __launch_bounds__(256) void gemm_mfma(const float* __restrict__ A,
                                                 const u16* __restrict__ Wh,
                                                 const u16* __restrict__ Wl,
                                                 u16* __restrict__ C, int M) {
    constexpr int NT = NOUT / 16;
    const int tid = threadIdx.x;
    const int w = tid >> 6, l = tid & 63;
    const int m = l & 15, q = l >> 4;

    int arow = blockIdx.x * 64 + w * 16 + m;
    const float* Ar = A + (size_t)min(arow, M - 1) * 128;

    f32x4 acc[NT] = {};

#pragma unroll
    for (int kc = 0; kc < 4; ++kc) {
        float p[8];
        *(float4*)&p[0] = *(const float4*)(Ar + kc * 32 + q * 8);
        *(float4*)&p[4] = *(const float4*)(Ar + kc * 32 + q * 8 + 4);
        short8 ah, al;
#pragma unroll
        for (int j = 0; j < 8; ++j) {
            u16 h = f2bf(p[j]);
            ah[j] = (short)h;
            al[j] = (short)f2bf(p[j] - bfval(h));
        }
#pragma unroll
        for (int t = 0; t < NT; ++t) {
            size_t bo = ((size_t)(t * 4 + kc) * 64 + l) * 8;
            short8 bh = *(const short8*)(Wh + bo);
            short8 bl = *(const short8*)(Wl + bo);
            acc[t] = __builtin_amdgcn_mfma_f32_16x16x32_bf16(ah, bh, acc[t], 0, 0, 0);
            acc[t] = __builtin_amdgcn_mfma_f32_16x16x32_bf16(al, bh, acc[t], 0, 0, 0);
            acc[t] = __builtin_amdgcn_mfma_f32_16x16x32_bf16(ah, bl, acc[t], 0, 0, 0);
        }
    }

    int growbase = blockIdx.x * 64 + w * 16 + q * 4;
#pragma unroll
    for (int t = 0; t < NT; ++t)
#pragma unroll
        for (int r = 0; r < 4; ++r) {
            int grow = growbase + r;
            if (grow < M) C[(size_t)grow * NOUT + t * 16 + m] = f2bf(acc[t][r]);
        }
}

// ---- MFMA GEMM, K=128, bf16 A (exact, 2-term: A*Wh + A*Wl), NOUT=64 --------

__global__ __launch_bounds__(256) void gemm_mfma_bf(const u16* __restrict__ A,
                                                    const u16* __restrict__ Wh,
                                                    const u16* __restrict__ Wl,
                                                    u16* __restrict__ C, int M) {
    constexpr int NT = 4;
    const int tid = threadIdx.x;
    const int w = tid >> 6, l = tid & 63;
    const int m = l & 15, q = l >> 4;

    int arow = blockIdx.x * 64 + w * 16 + m;
    const u16* Ar = A + (size_t)min(arow, M - 1) * 128;

    f32x4 acc[NT] = {};

#pragma unroll
    for (int kc = 0; kc < 4; ++kc) {
        short8 ah = *(const short8*)(Ar + kc * 32 + q * 8);
#pragma unroll
        for (int t = 0; t < NT; ++t) {
            size_t bo = ((size_t)(t * 4 + kc) * 64 + l) * 8;
            short8 bh = *(const short8*)(Wh + bo);
            short8 bl = *(const short8*)(Wl + bo);
            acc[t] = __builtin_amdgcn_mfma_f32_16x16x32_bf16(ah, bh, acc[t], 0, 0, 0);
            acc[t] = __builtin_amdgcn_mfma_f32_16x16x32_bf16(ah, bl, acc[t], 0, 0, 0);
        }
    }

    int growbase = blockIdx.x * 64 + w * 16 + q * 4;
#pragma unroll
    for (int t = 0; t < NT; ++t)
#pragma unroll
        for (int r = 0; r < 4; ++r) {
            int grow = growbase + r;
            if (grow < M) C[(size_t)grow * 64 + t * 16 + m] = f2bf(acc[t][r]);
        }
}

// ---------------- normalized aggregation (one wave per node, bf16 H) --------
// Sharded ELL: valid slots [0,c0) u [32,32+c1); lane i takes the i-th valid
// slot. Self-loop folded as edge #ne. OUTBF: write bf16 (layer 1) vs fp32.

template <int F, bool RELU, bool OUTBF>
__global__ __launch_bounds__(256) void aggregate(const u16* __restrict__ H,
                                                 const u16* __restrict__ ell,
                                                 const int* __restrict__ cnt,
                                                 const float* __restrict__ bias,
                                                 void* __restrict__ outp) {
    const int tid = threadIdx.x;
    const int node = (int)((blockIdx.x * 256 + tid) >> 6);
    if (node >= NN) return;
    const int lane = tid & 63;

    const int c0r = cnt[node], c1r = cnt[NPAD + node];
    const int c0 = min(c0r, 32), c1 = min(c1r, 32);
    const int ne = min(c0 + c1, 63);        // keep one lane for self-loop
    const float di = rsqrtf((float)(c0r + c1r + 1));
    int slot = (lane < c0) ? lane : 32 + (lane - c0);
    int   s_l = (lane < ne) ? (int)ell[(size_t)node * CAP + slot] : node;
    float n_l = (lane <= ne)
                    ? rsqrtf((float)(cnt[s_l] + cnt[NPAD + s_l] + 1)) * di
                    : 0.0f;

    constexpr int G = (F == 128) ? 4 : 8;  // edges gathered per step
    constexpr int L = 64 / G;              // lanes per edge (16B each)
    const int g = lane / L;
    const int ci = lane & (L - 1);

    const int m = ne + 1;
    const int mPad = (m + 2 * G - 1) & ~(2 * G - 1);

    float acc[8] = {0, 0, 0, 0, 0, 0, 0, 0};
    for (int j = 0; j < mPad; j += 2 * G) {
        int   sA = __shfl(s_l, j + g);
        float nA = __shfl(n_l, j + g);
        int   sB = __shfl(s_l, j + G + g);
        float nB = __shfl(n_l, j + G + g);
        uint4 vA = *(const uint4*)(H + (size_t)sA * F + ci * 8);
        uint4 vB = *(const uint4*)(H + (size_t)sB * F + ci * 8);
        acc[0] += nA * bf_lo(vA.x); acc[1] += nA * bf_hi(vA.x);
        acc[2] += nA * bf_lo(vA.y); acc[3] += nA * bf_hi(vA.y);
        acc[4] += nA * bf_lo(vA.z); acc[5] += nA * bf_hi(vA.z);
        acc[6] += nA * bf_lo(vA.w); acc[7] += nA * bf_hi(vA.w);
        acc[0] += nB * bf_lo(vB.x); acc[1] += nB * bf_hi(vB.x);
        acc[2] += nB * bf_lo(vB.y); acc[3] += nB * bf_hi(vB.y);
        acc[4] += nB * bf_lo(vB.z); acc[5] += nB * bf_hi(vB.z);
        acc[6] += nB * bf_lo(vB.w); acc[7] += nB * bf_hi(vB.w);
    }

#pragma unroll
    for (int i = 0; i < 8; ++i) {
        if (F == 64) acc[i] += __shfl_xor(acc[i], 8);
        acc[i] += __shfl_xor(acc[i], 16);
        acc[i] += __shfl_xor(acc[i], 32);
    }

    const int active = (F == 128) ? 32 : 16;
    if (lane < active) {
        int part, c0i;
        if (F == 128) { part = lane >> 4;       c0i = (lane & 15) * 8 + part * 4; }
        else          { part = (lane >> 3) & 1; c0i = (lane & 7) * 8 + part * 4; }
        float4 b4 = *(const float4*)(bias + c0i);
        float4 o = make_float4(acc[part * 4 + 0] + b4.x, acc[part * 4 + 1] + b4.y,
                               acc[part * 4 + 2] + b4.z, acc[part * 4 + 3] + b4.w);
        if (RELU) { o.x = fmaxf(o.x, 0.f); o.y = fmaxf(o.y, 0.f);
                    o.z = fmaxf(o.z, 0.f); o.w = fmaxf(o.w, 0.f); }
        if (OUTBF) {
            u16* out = (u16*)outp;
            *(ushort4*)(out + (size_t)node * F + c0i) =
                make_ushort4(f2bf(o.x), f2bf(o.y), f2bf(o.z), f2bf(o.w));
        } else {
            float* out = (float*)outp;
            *(float4*)(out + (size_t)node * F + c0i) = o;
        }
    }
}

// ---------------- launch ----------------

extern "C" void kernel_launch(void* const* d_in, const int* in_sizes, int n_in,
                              void* d_out, int out_size, void* d_ws, size_t ws_size,
                              hipStream_t stream) {
    const float* x  = (const float*)d_in[0];
    const int*   ei = (const int*)d_in[1];
    const float* W1 = (const float*)d_in[2];
    const float* b1 = (const float*)d_in[3];
    const float* W2 = (const float*)d_in[4];
    const float* b2 = (const float*)d_in[5];
    float* out = (float*)d_out;

    char* ws = (char*)d_ws;
    size_t off = 0;
    int* cnt = (int*)ws;                     off += (size_t)2 * NPAD * 4;
    u16* ell = (u16*)(ws + off);             off += (size_t)NN * CAP * 2;
    off = (off + 255) & ~(size_t)255;
    u16* W1h = (u16*)(ws + off);             off += 16384 * 2;
    u16* W1l = (u16*)(ws + off);             off += 16384 * 2;
    u16* W2h = (u16*)(ws + off);             off += 8192 * 2;
    u16* W2l = (u16*)(ws + off);             off += 8192 * 2;
    off = (off + 255) & ~(size_t)255;
    u16* Hbf = (u16*)(ws + off);             off += (size_t)NN * 128 * 2;  // H1 / H2
    u16* Abf = (u16*)(ws + off);             off += (size_t)NN * 128 * 2;  // agg1 out

    prep_w<<<128, 256, 0, stream>>>(W1, W2, W1h, W1l, W2h, W2l, cnt);
    build_ell<<<1600, 256, 0, stream>>>(ei, cnt, ell);

    // layer 1: H1 = x@W1 (bf16) ; agg+bias+relu -> Abf (bf16)
    gemm_mfma<128><<<(NN + 63) / 64, 256, 0, stream>>>(x, W1h, W1l, Hbf, NN);
    aggregate<128, true, true><<<(NN + 3) / 4, 256, 0, stream>>>(Hbf, ell, cnt, b1, Abf);

    // layer 2: H2 = Abf@W2 (bf16, exact-A 2-term) ; agg+bias -> out (fp32)
    gemm_mfma_bf<<<(NN + 63) / 64, 256, 0, stream>>>(Abf, W2h, W2l, Hbf, NN);
    aggregate<64, false, false><<<(NN + 3) / 4, 256, 0, stream>>>(Hbf, ell, cnt, b2, out);
}